// Round 9
// baseline (200.243 us; speedup 1.0000x reference)
//
#include <hip/hip_runtime.h>
#include <cfloat>
#include <cstdint>

#define B_  64
#define T_  1024
#define D_  128
#define NE  512            // clip limit; emb has NE+1 = 513 rows
#define P_  (B_*T_)        // 65536 positions

// d_out flat offsets (float32), in reference return order
#define O_KH   0
#define O_ENC  (P_*D_)             // 8388608
#define O_V    (O_ENC + P_)        // 8454144
#define O_LH   (O_V + 1)           // 8454145
#define O_LN   (O_LH + P_)         // 8519681
#define O_EM   (O_LN + P_)         // 8585217
#define O_LED  (O_EM + 1)          // 8585218

typedef __attribute__((ext_vector_type(8))) short bf16x8;
typedef __attribute__((ext_vector_type(4))) float floatx4;
typedef unsigned long long u64;

// hi = truncate-to-bf16(x), lo = truncate-to-bf16(x - hi); pack 8 floats ->
// two uint4 (8 bf16 each, k-ascending little-endian)
__device__ __forceinline__ void pack8(const float4& a, const float4& b,
                                      uint4& h, uint4& l)
{
    float v[8] = {a.x,a.y,a.z,a.w,b.x,b.y,b.z,b.w};
    unsigned hw[4], lw[4];
    #pragma unroll
    for (int e = 0; e < 4; e++) {
        const unsigned ua = __float_as_uint(v[2*e]);
        const unsigned ub = __float_as_uint(v[2*e+1]);
        const float fa = __uint_as_float(ua & 0xffff0000u);
        const float fb = __uint_as_float(ub & 0xffff0000u);
        const unsigned da = __float_as_uint(v[2*e]   - fa);
        const unsigned db = __float_as_uint(v[2*e+1] - fb);
        hw[e] = (ub & 0xffff0000u) | (ua >> 16);
        lw[e] = (db & 0xffff0000u) | (da >> 16);
    }
    h = make_uint4(hw[0],hw[1],hw[2],hw[3]);
    l = make_uint4(lw[0],lw[1],lw[2],lw[3]);
}

__device__ __forceinline__ u64 shflx64(u64 v, int d)
{
    const int lo = __shfl_xor((int)(unsigned)(v & 0xffffffffULL), d);
    const int hi = __shfl_xor((int)(unsigned)(v >> 32), d);
    return ((u64)(unsigned)hi << 32) | (unsigned)lo;
}

// monotone float->uint map (strictly increasing) — EXACT, no quantization
__device__ __forceinline__ unsigned sortkey(float f)
{
    const unsigned b = __float_as_uint(f);
    return b ^ (unsigned)(((int)b >> 31) | (int)0x80000000);
}

// ---------------------------------------------------------------------------
// kF: pre-convert emb (rows 0..511) to bf16 hi/lo in MFMA A-frag layout AND
// compute sq[n] = ||emb_n||^2 (quad shuffle reduce).
// ---------------------------------------------------------------------------
__global__ __launch_bounds__(256) void kF(const float* __restrict__ emb,
                                          unsigned short* __restrict__ ehi,
                                          unsigned short* __restrict__ elo,
                                          float* __restrict__ sq)
{
    const int t = blockIdx.x * 256 + threadIdx.x;     // 0..2047
    const int n = t >> 2, kst = t & 3;
    const float4* src = (const float4*)(emb + (size_t)n * D_ + kst * 32);
    float ss = 0.f;
    #pragma unroll
    for (int g = 0; g < 4; g++) {
        const float4 a = src[2*g], b = src[2*g+1];
        ss += a.x*a.x + a.y*a.y + a.z*a.z + a.w*a.w
            + b.x*b.x + b.y*b.y + b.z*b.z + b.w*b.w;
        uint4 h, l;
        pack8(a, b, h, l);
        const int f = ((n >> 4) * 4 + kst) * 4 + g;
        *(uint4*)(ehi + (size_t)f*128 + (size_t)(n & 15)*8) = h;
        *(uint4*)(elo + (size_t)f*128 + (size_t)(n & 15)*8) = l;
    }
    ss += __shfl_xor(ss, 1);
    ss += __shfl_xor(ss, 2);
    if (kst == 0) sq[n] = ss;
}

// ---------------------------------------------------------------------------
// kG: pre-convert ks (65536 rows) to bf16 hi/lo in MFMA B-frag tile layout.
// Destination is d_out's key_hard region (32 MiB) used as scratch: written
// here, read by kA, overwritten by kC (stream-ordered, no hazard).
// ---------------------------------------------------------------------------
__global__ __launch_bounds__(256) void kG(const float* __restrict__ ks,
                                          unsigned short* __restrict__ khi,
                                          unsigned short* __restrict__ klo)
{
    const int pt  = blockIdx.x;               // p-tile 0..1023
    const int kh  = threadIdx.x >> 6;         // k-quarter 0..3
    const int row = threadIdx.x & 63;         // p within tile
    const float4* src = (const float4*)(ks + ((size_t)pt*64 + row)*D_ + kh*32);
    #pragma unroll
    for (int g = 0; g < 4; g++) {
        uint4 h, l;
        pack8(src[2*g], src[2*g+1], h, l);
        const size_t o = ((size_t)(pt*16 + kh*4 + g)*64 + row)*8;
        *(uint4*)(khi + o) = h;
        *(uint4*)(klo + o) = l;
    }
}

// ---------------------------------------------------------------------------
// kA: barrier-free transposed MFMA GEMM (M = n, N = p). ONE chunk (64 n) per
// wave; grid 2048 = 1024 p-tiles x 2 chunk-halves. No LDS, no __syncthreads.
// hi/lo 3-pass MFMA. Outputs: bits (bit63=0 except chunk 7; patched in kB),
// sfirst/slast chunk-edge S, EXACT chunk argmin as (u32 sortkey, u16 index).
// ---------------------------------------------------------------------------
__global__ __launch_bounds__(256) void kA(const float* __restrict__ sq,
                                          const unsigned short* __restrict__ ehi,
                                          const unsigned short* __restrict__ elo,
                                          const unsigned short* __restrict__ khi,
                                          const unsigned short* __restrict__ klo,
                                          u64* __restrict__ bits,
                                          float* __restrict__ sfirst,
                                          float* __restrict__ slast,
                                          unsigned* __restrict__ mins,
                                          unsigned short* __restrict__ mini16)
{
    const int tid  = threadIdx.x;
    const int lane = tid & 63;
    const int wv   = tid >> 6;
    const int m    = lane & 15;               // p within 16-tile
    const int q    = lane >> 4;               // quad
    const int pt   = blockIdx.x >> 1;
    const int p0   = pt * 64;
    const int ch   = (blockIdx.x & 1) * 4 + wv;   // chunk 0..7
    const int nb   = ch * 64;

    floatx4 acc[4][4];
    #pragma unroll
    for (int i = 0; i < 4; i++)
        #pragma unroll
        for (int j = 0; j < 4; j++)
            #pragma unroll
            for (int r = 0; r < 4; r++) acc[i][j][r] = 0.f;

    #pragma unroll 1
    for (int kst = 0; kst < 4; kst++) {
        bf16x8 ah[4], al[4], bh[4], bl[4];
        #pragma unroll
        for (int i = 0; i < 4; i++) {
            const int off = (((ch*4 + i) * 4 + kst) * 4 + q) * 128 + m*8;
            ah[i] = *(const bf16x8*)(ehi + off);
            al[i] = *(const bf16x8*)(elo + off);
        }
        #pragma unroll
        for (int j = 0; j < 4; j++) {
            const int off = ((pt*16 + kst*4 + q) * 64 + j*16 + m) * 8;
            bh[j] = *(const bf16x8*)(khi + off);
            bl[j] = *(const bf16x8*)(klo + off);
        }
        #pragma unroll
        for (int i = 0; i < 4; i++)
            #pragma unroll
            for (int j = 0; j < 4; j++)
                acc[i][j] = __builtin_amdgcn_mfma_f32_16x16x32_bf16(ah[i], bh[j], acc[i][j], 0, 0, 0);
        #pragma unroll
        for (int i = 0; i < 4; i++)
            #pragma unroll
            for (int j = 0; j < 4; j++)
                acc[i][j] = __builtin_amdgcn_mfma_f32_16x16x32_bf16(ah[i], bl[j], acc[i][j], 0, 0, 0);
        #pragma unroll
        for (int i = 0; i < 4; i++)
            #pragma unroll
            for (int j = 0; j < 4; j++)
                acc[i][j] = __builtin_amdgcn_mfma_f32_16x16x32_bf16(al[i], bh[j], acc[i][j], 0, 0, 0);
    }

    // ---- epilogue (register-local; non-terminal bit63 patched in kB) ----
    float sa[4][4];
    #pragma unroll
    for (int i = 0; i < 4; i++) {
        const float4 s4 = *(const float4*)(sq + nb + i*16 + q*4);
        sa[i][0]=s4.x; sa[i][1]=s4.y; sa[i][2]=s4.z; sa[i][3]=s4.w;
    }
    #pragma unroll
    for (int j = 0; j < 4; j++) {
        float S[4][4];
        #pragma unroll
        for (int i = 0; i < 4; i++)
            #pragma unroll
            for (int r = 0; r < 4; r++)
                S[i][r] = fmaf(-2.f, acc[i][j][r], sa[i][r]);

        // neighbor S at quad/tile boundaries
        float nq[4], ni[4];
        #pragma unroll
        for (int i = 0; i < 4; i++) nq[i] = __shfl_down(S[i][0], 16);
        #pragma unroll
        for (int i = 0; i < 3; i++) ni[i] = __shfl(S[i+1][0], m);
        ni[3] = 0.f;

        u64 w = 0;
        #pragma unroll
        for (int i = 0; i < 4; i++) {
            #pragma unroll
            for (int r = 0; r < 3; r++)
                w |= (u64)(S[i][r] <= S[i][r+1]) << (16*i + 4*q + r);
            if (!(i == 3 && q == 3)) {
                const float nxt = (q < 3) ? nq[i] : ni[i];
                w |= (u64)(S[i][3] <= nxt) << (16*i + 4*q + 3);
            }
        }
        if (ch == 7 && q == 3) w |= 1ULL << 63;   // n=511 clip -> stay
        w |= shflx64(w, 16);
        w |= shflx64(w, 32);

        // chunk argmin, EXACT (first-index tie-break)
        float mv = S[0][0]; int mi_ = nb + q*4;
        #pragma unroll
        for (int i = 0; i < 4; i++)
            #pragma unroll
            for (int r = 0; r < 4; r++) {
                if (i == 0 && r == 0) continue;
                const int nid = nb + 16*i + 4*q + r;
                if (S[i][r] < mv) { mv = S[i][r]; mi_ = nid; }
            }
        #pragma unroll
        for (int d = 16; d <= 32; d <<= 1) {
            const float v2 = __shfl_xor(mv, d);
            const int   i2 = __shfl_xor(mi_, d);
            if (v2 < mv || (v2 == mv && i2 < mi_)) { mv = v2; mi_ = i2; }
        }

        const size_t pg = (size_t)(p0 + j*16 + m);
        if (q == 0) {
            bits  [pg*8 + ch] = w;
            sfirst[pg*8 + ch] = S[0][0];
            mins  [pg*8 + ch] = sortkey(mv);
            mini16[pg*8 + ch] = (unsigned short)mi_;
        }
        if (q == 3) slast[pg*8 + ch] = S[3][3];
    }
}

// ---------------------------------------------------------------------------
// kB: one wave per b. ind0 from EXACT u64-key argmin at t=0, then 16 windows
// of 64 scan steps; double-buffered window prefetch + 7-boundary bit63 patch
// in registers + 64 unrolled readlane scan steps (scalar pipe).
// ---------------------------------------------------------------------------
struct KBwin { u64 W[8]; float F[8]; float L[8]; };

__global__ __launch_bounds__(64) void kB(const float* __restrict__ ks,
                                         const float* __restrict__ emb,
                                         const unsigned char* __restrict__ mask,
                                         const u64* __restrict__ bits,
                                         const float* __restrict__ sfirst,
                                         const float* __restrict__ slast,
                                         const unsigned* __restrict__ mins,
                                         const unsigned short* __restrict__ mini16,
                                         int* __restrict__ enci,
                                         float* __restrict__ out)
{
    const int b    = blockIdx.x;
    const int lane = threadIdx.x;
    const size_t p0 = (size_t)b * T_;

    // ind0: S[512] exact + 8 exact chunk keys
    const float2 e = ((const float2*)(emb + (size_t)512*D_))[lane];
    const float2 k = ((const float2*)(ks  + p0*D_))[lane];
    float s5 = e.x*(e.x - 2.f*k.x) + e.y*(e.y - 2.f*k.y);
    #pragma unroll
    for (int m = 32; m >= 1; m >>= 1) s5 += __shfl_xor(s5, m);

    u64 kk = ~0ULL;
    if (lane < 8)       kk = ((u64)mins[p0*8 + lane] << 32) | (u64)mini16[p0*8 + lane];
    else if (lane == 8) kk = ((u64)sortkey(s5) << 32) | 512ULL;
    #pragma unroll
    for (int d = 1; d <= 8; d <<= 1) {
        const u64 o = shflx64(kk, d);
        kk = (o < kk) ? o : kk;
    }
    const int mi = __shfl((int)(unsigned)(kk & 0xffffffffULL), 0);
    int cur = (mi < NE) ? mi : NE - 1;
    if (mask[b]) cur = 0;
    if (lane == 0) { enci[p0] = cur; out[O_ENC + p0] = (float)cur; }

    KBwin wa, wb;

    auto loadwin = [&](KBwin& d, int t0) {
        const int t = t0 + lane;
        if (t < T_) {
            const ulonglong2* bp = (const ulonglong2*)(bits + (p0 + t)*8);
            const ulonglong2 w01 = bp[0], w23 = bp[1], w45 = bp[2], w67 = bp[3];
            d.W[0]=w01.x; d.W[1]=w01.y; d.W[2]=w23.x; d.W[3]=w23.y;
            d.W[4]=w45.x; d.W[5]=w45.y; d.W[6]=w67.x; d.W[7]=w67.y;
            const float4* fp = (const float4*)(sfirst + (p0 + t)*8);
            const float4 f0 = fp[0], f1 = fp[1];
            d.F[0]=f0.x; d.F[1]=f0.y; d.F[2]=f0.z; d.F[3]=f0.w;
            d.F[4]=f1.x; d.F[5]=f1.y; d.F[6]=f1.z; d.F[7]=f1.w;
            const float4* lp = (const float4*)(slast + (p0 + t)*8);
            const float4 l0 = lp[0], l1 = lp[1];
            d.L[0]=l0.x; d.L[1]=l0.y; d.L[2]=l0.z; d.L[3]=l0.w;
            d.L[4]=l1.x; d.L[5]=l1.y; d.L[6]=l1.z; d.L[7]=l1.w;
        } else {
            #pragma unroll
            for (int c = 0; c < 8; c++) { d.W[c] = ~0ULL; d.F[c] = 1.f; d.L[c] = 0.f; }
        }
    };

    auto scanwin = [&](KBwin& d, int t0) {
        #pragma unroll
        for (int c = 0; c < 7; c++)
            d.W[c] |= (u64)(d.L[c] <= d.F[c+1]) << 63;

        const int w0   = cur >> 6;
        const int off0 = cur & 63;
        u64 a = d.W[0];
        #pragma unroll
        for (int c = 1; c < 8; c++) a = (w0 == c) ? d.W[c] : a;
        u64 bn = ~0ULL;
        #pragma unroll
        for (int c = 1; c < 8; c++) bn = (w0 == c-1) ? d.W[c] : bn;
        const u64 u = (off0 == 0) ? a : ((a >> off0) | (bn << (64 - off0)));

        const unsigned ulo = (unsigned)u;
        const unsigned uhi = (unsigned)(u >> 32);
        int doff = 0;
        int myenc = cur;
        #pragma unroll
        for (int j = 0; j < 64; j++) {
            const unsigned slo = (unsigned)__builtin_amdgcn_readlane((int)ulo, j);
            const unsigned shi = (unsigned)__builtin_amdgcn_readlane((int)uhi, j);
            const u64 word = ((u64)shi << 32) | slo;
            const int bit = (int)((word >> doff) & 1ULL);
            doff += 1 - bit;
            if (lane == j) myenc = cur + doff;
        }
        cur += doff;
        const int t = t0 + lane;
        if (t < T_) {
            enci[p0 + t] = myenc;
            out[O_ENC + p0 + t] = (float)myenc;
        }
    };

    loadwin(wa, 1);
    #pragma unroll 1
    for (int wp = 0; wp < 8; wp++) {
        const int t0a = 1 + wp*128;
        loadwin(wb, t0a + 64);
        scanwin(wa, t0a);
        if (wp < 7) loadwin(wa, t0a + 128);
        scanwin(wb, t0a + 64);
    }
}

// ---------------------------------------------------------------------------
// kC: one wave per position, quad-split. Quad q computes one dot:
// q0: S[eh], q1: S[en], q2: S[512], q3: ||ks||^2. Global argmin via EXACT
// u64 keys. pm is SELECTED (pm=ph / pn / p5) when mi hits a special case —
// bitwise-guaranteed equality regardless of codegen/contraction (this was
// the r7/r8 bug: recomputed pm in different expression context could round
// differently from ph under -ffp-contract, flipping pm<ph at mi==eh and
// spuriously subtracting lm ~ 200). Recompute only for genuinely distinct mi
// (real gap -> rounding-safe).
// ---------------------------------------------------------------------------
__global__ __launch_bounds__(256) void kC(const float* __restrict__ ks,
                                          const float* __restrict__ emb,
                                          const int* __restrict__ enci,
                                          const unsigned* __restrict__ mins,
                                          const unsigned short* __restrict__ mini16,
                                          float* __restrict__ out,
                                          float* __restrict__ energy)
{
    const int lane = threadIdx.x & 63;
    const size_t p = (size_t)blockIdx.x * 4 + (threadIdx.x >> 6);
    const int q  = lane >> 4;
    const int qm = lane & 15;

    const int eh = enci[p];
    const int en = (eh + 1 < NE) ? eh + 1 : NE - 1;
    const int row = (q == 0) ? eh : ((q == 1) ? en : 512);

    const float4* ksp = (const float4*)(ks + p*D_);
    const float4 k1 = ksp[qm*2], k2 = ksp[qm*2 + 1];
    const float4* ep = (const float4*)(emb + (size_t)row*D_);
    const float4 e1 = ep[qm*2], e2 = ep[qm*2 + 1];

    float d;
    if (q == 3) {
        d = k1.x*k1.x + k1.y*k1.y + k1.z*k1.z + k1.w*k1.w
          + k2.x*k2.x + k2.y*k2.y + k2.z*k2.z + k2.w*k2.w;
    } else {
        d = e1.x*(e1.x - 2.f*k1.x) + e1.y*(e1.y - 2.f*k1.y)
          + e1.z*(e1.z - 2.f*k1.z) + e1.w*(e1.w - 2.f*k1.w)
          + e2.x*(e2.x - 2.f*k2.x) + e2.y*(e2.y - 2.f*k2.y)
          + e2.z*(e2.z - 2.f*k2.z) + e2.w*(e2.w - 2.f*k2.w);
    }
    #pragma unroll
    for (int s = 1; s <= 8; s <<= 1) d += __shfl_xor(d, s);

    const float ph  = __shfl(d, 0);
    const float pn  = __shfl(d, 16);
    const float p5  = __shfl(d, 32);
    const float sqk = __shfl(d, 48);

    // global argmin via EXACT u64 keys (8 chunk keys + S[512] key)
    u64 kk = ~0ULL;
    if (lane < 8)       kk = ((u64)mins[p*8 + lane] << 32) | (u64)mini16[p*8 + lane];
    else if (lane == 8) kk = ((u64)sortkey(p5) << 32) | 512ULL;
    #pragma unroll
    for (int s = 1; s <= 8; s <<= 1) {
        const u64 o = shflx64(kk, s);
        kk = (o < kk) ? o : kk;
    }
    const int mi = __shfl((int)(unsigned)(kk & 0xffffffffULL), 0);

    // pm: SELECT for special cases (bitwise equality), recompute otherwise
    float pm;
    if (mi == eh)      pm = ph;
    else if (mi == en) pm = pn;
    else if (mi == 512) pm = p5;
    else {
        const float4* mp = (const float4*)(emb + (size_t)mi*D_);
        const float4 m1 = mp[qm*2], m2 = mp[qm*2 + 1];
        float dm = m1.x*(m1.x - 2.f*k1.x) + m1.y*(m1.y - 2.f*k1.y)
                 + m1.z*(m1.z - 2.f*k1.z) + m1.w*(m1.w - 2.f*k1.w)
                 + m2.x*(m2.x - 2.f*k2.x) + m2.y*(m2.y - 2.f*k2.y)
                 + m2.z*(m2.z - 2.f*k2.z) + m2.w*(m2.w - 2.f*k2.w);
        #pragma unroll
        for (int s = 1; s <= 8; s <<= 1) dm += __shfl_xor(dm, s);
        pm = __shfl(dm, 0);
    }

    // key_hard: quad0 holds emb[eh] slices; kh = ks + (emb - ks) in fp32
    if (q == 0) {
        float4 o1, o2;
        o1.x = k1.x + (e1.x - k1.x); o1.y = k1.y + (e1.y - k1.y);
        o1.z = k1.z + (e1.z - k1.z); o1.w = k1.w + (e1.w - k1.w);
        o2.x = k2.x + (e2.x - k2.x); o2.y = k2.y + (e2.y - k2.y);
        o2.z = k2.z + (e2.z - k2.z); o2.w = k2.w + (e2.w - k2.w);
        ((float4*)(out + p*D_))[qm*2]     = o1;
        ((float4*)(out + p*D_))[qm*2 + 1] = o2;
    }

    if (lane == 0) {
        const float lh = 1.2f * (sqk + ph);
        const float ln = 1.2f * (sqk + pn);
        const float lm = 1.2f * (sqk + pm);
        out[O_LH + p] = lh - ln - ((pm < ph) ? lm : 0.f);
        out[O_LN + p] = ln - lh - ((pm < pn) ? lm : 0.f);
        energy[p] = 1.2f * (pn - ph);
    }
}

// ---------------------------------------------------------------------------
// kD1: per-256-position partial sums (energy, energy-descent terms)
// ---------------------------------------------------------------------------
__global__ __launch_bounds__(256) void kD1(const float* __restrict__ energy,
                                           const int* __restrict__ enci,
                                           double2* __restrict__ part)
{
    __shared__ double sA[256], sB[256];
    const int p = blockIdx.x * 256 + threadIdx.x;
    const float e = energy[p];
    double se = (double)e;
    double sl = 0.0;
    if ((p & (T_-1)) < T_-1) {
        const float ec = (enci[p+1] == enci[p]) ? (energy[p+1] - e) : 0.f;
        sl = (double)fmaxf(ec + (float)(1e-6/512.0), 0.f);
    }
    sA[threadIdx.x] = se; sB[threadIdx.x] = sl;
    __syncthreads();
    for (int s = 128; s >= 1; s >>= 1) {
        if (threadIdx.x < (unsigned)s) {
            sA[threadIdx.x] += sA[threadIdx.x+s];
            sB[threadIdx.x] += sB[threadIdx.x+s];
        }
        __syncthreads();
    }
    if (threadIdx.x == 0) { part[blockIdx.x] = make_double2(sA[0], sB[0]); }
}

// ---------------------------------------------------------------------------
// kD2: final reduce of 256 partials + v = max over b of (enc_last - enc_first)
// ---------------------------------------------------------------------------
__global__ __launch_bounds__(256) void kD2(const double2* __restrict__ part,
                                           const int* __restrict__ enci,
                                           float* __restrict__ out)
{
    __shared__ double sA[256], sB[256];
    const double2 pv = part[threadIdx.x];
    sA[threadIdx.x] = pv.x; sB[threadIdx.x] = pv.y;
    __syncthreads();
    for (int s = 128; s >= 1; s >>= 1) {
        if (threadIdx.x < (unsigned)s) {
            sA[threadIdx.x] += sA[threadIdx.x+s];
            sB[threadIdx.x] += sB[threadIdx.x+s];
        }
        __syncthreads();
    }
    if (threadIdx.x < 64) {
        int v = enci[(size_t)threadIdx.x*T_ + T_-1] - enci[(size_t)threadIdx.x*T_];
        #pragma unroll
        for (int m = 32; m >= 1; m >>= 1) {
            const int v2 = __shfl_xor(v, m);
            v = (v2 > v) ? v2 : v;
        }
        if (threadIdx.x == 0) {
            out[O_V]   = (float)v;
            out[O_EM]  = (float)(sA[0] / (double)P_);
            out[O_LED] = (float)(sB[0] / (double)(B_*(T_-1)));
        }
    }
}

// ---------------------------------------------------------------------------
extern "C" void kernel_launch(void* const* d_in, const int* in_sizes, int n_in,
                              void* d_out, int out_size, void* d_ws, size_t ws_size,
                              hipStream_t stream)
{
    const float* ks  = (const float*)d_in[0];
    const float* emb = (const float*)d_in[1];
    const unsigned char* mask = (const unsigned char*)d_in[2];

    float* out = (float*)d_out;
    char* w = (char*)d_ws;
    u64*      bits   = (u64*)     (w);                                    // 4 MB
    float*    sfirst = (float*)   (w + (size_t) 4*1024*1024);             // 2 MB
    float*    slast  = (float*)   (w + (size_t) 6*1024*1024);             // 2 MB
    unsigned* mins   = (unsigned*)(w + (size_t) 8*1024*1024);             // 2 MB
    unsigned short* mini16 = (unsigned short*)(w + (size_t)10*1024*1024); // 1 MB
    int*      enci   = (int*)     (w + (size_t)11*1024*1024);             // 256 KB
    float*    energy = (float*)   (w + (size_t)11*1024*1024 + 256*1024);  // 256 KB
    float*    sq     = (float*)   (w + (size_t)11*1024*1024 + 512*1024);  // 4 KB
    double2*  part   = (double2*) (w + (size_t)11*1024*1024 + 516*1024);  // 4 KB
    unsigned short* ehi = (unsigned short*)(w + (size_t)11*1024*1024 + 640*1024); // 128 KB
    unsigned short* elo = (unsigned short*)(w + (size_t)11*1024*1024 + 768*1024); // 128 KB
    // ks bf16 frags live in d_out's key_hard region (32 MiB) as scratch:
    // written by kG, read by kA, overwritten by kC. Stream-ordered, no hazard.
    unsigned short* khi = (unsigned short*)d_out;                          // 16 MiB
    unsigned short* klo = (unsigned short*)((char*)d_out + (size_t)16*1024*1024); // 16 MiB

    kF <<<8,    256, 0, stream>>>(emb, ehi, elo, sq);
    kG <<<1024, 256, 0, stream>>>(ks, khi, klo);
    kA <<<2048, 256, 0, stream>>>(sq, ehi, elo, khi, klo, bits, sfirst, slast, mins, mini16);
    kB <<<B_,   64,  0, stream>>>(ks, emb, mask, bits, sfirst, slast, mins, mini16, enci, out);
    kC <<<P_/4, 256, 0, stream>>>(ks, emb, enci, mins, mini16, out, energy);
    kD1<<<256,  256, 0, stream>>>(energy, enci, part);
    kD2<<<1,    256, 0, stream>>>(part, enci, out);
}

// Round 10
// 194.467 us; speedup vs baseline: 1.0297x; 1.0297x over previous
//
#include <hip/hip_runtime.h>
#include <cfloat>
#include <cstdint>

#define B_  64
#define T_  1024
#define D_  128
#define NE  512            // clip limit; emb has NE+1 = 513 rows
#define P_  (B_*T_)        // 65536 positions

// d_out flat offsets (float32), in reference return order
#define O_KH   0
#define O_ENC  (P_*D_)             // 8388608
#define O_V    (O_ENC + P_)        // 8454144
#define O_LH   (O_V + 1)           // 8454145
#define O_LN   (O_LH + P_)         // 8519681
#define O_EM   (O_LN + P_)         // 8585217
#define O_LED  (O_EM + 1)          // 8585218

typedef __attribute__((ext_vector_type(8))) short bf16x8;
typedef __attribute__((ext_vector_type(4))) float floatx4;
typedef unsigned long long u64;

// hi = truncate-to-bf16(x), lo = truncate-to-bf16(x - hi); pack 8 floats ->
// two uint4 (8 bf16 each, k-ascending little-endian)
__device__ __forceinline__ void pack8(const float4& a, const float4& b,
                                      uint4& h, uint4& l)
{
    float v[8] = {a.x,a.y,a.z,a.w,b.x,b.y,b.z,b.w};
    unsigned hw[4], lw[4];
    #pragma unroll
    for (int e = 0; e < 4; e++) {
        const unsigned ua = __float_as_uint(v[2*e]);
        const unsigned ub = __float_as_uint(v[2*e+1]);
        const float fa = __uint_as_float(ua & 0xffff0000u);
        const float fb = __uint_as_float(ub & 0xffff0000u);
        const unsigned da = __float_as_uint(v[2*e]   - fa);
        const unsigned db = __float_as_uint(v[2*e+1] - fb);
        hw[e] = (ub & 0xffff0000u) | (ua >> 16);
        lw[e] = (db & 0xffff0000u) | (da >> 16);
    }
    h = make_uint4(hw[0],hw[1],hw[2],hw[3]);
    l = make_uint4(lw[0],lw[1],lw[2],lw[3]);
}

__device__ __forceinline__ u64 shflx64(u64 v, int d)
{
    const int lo = __shfl_xor((int)(unsigned)(v & 0xffffffffULL), d);
    const int hi = __shfl_xor((int)(unsigned)(v >> 32), d);
    return ((u64)(unsigned)hi << 32) | (unsigned)lo;
}

// monotone float->uint map (strictly increasing) — EXACT, no quantization
__device__ __forceinline__ unsigned sortkey(float f)
{
    const unsigned b = __float_as_uint(f);
    return b ^ (unsigned)(((int)b >> 31) | (int)0x80000000);
}

// ---------------------------------------------------------------------------
// kFG: fused pre-conversion. Blocks 0..1023: ks -> bf16 hi/lo B-frag tiles
// (into d_out scratch). Blocks 1024..1031: emb -> bf16 hi/lo A-frag layout
// + sq[n] = ||emb_n||^2.
// ---------------------------------------------------------------------------
__global__ __launch_bounds__(256) void kFG(const float* __restrict__ ks,
                                           const float* __restrict__ emb,
                                           unsigned short* __restrict__ ehi,
                                           unsigned short* __restrict__ elo,
                                           float* __restrict__ sq,
                                           unsigned short* __restrict__ khi,
                                           unsigned short* __restrict__ klo)
{
    if (blockIdx.x < 1024) {
        const int pt  = blockIdx.x;               // p-tile 0..1023
        const int kh  = threadIdx.x >> 6;         // k-quarter 0..3
        const int row = threadIdx.x & 63;         // p within tile
        const float4* src = (const float4*)(ks + ((size_t)pt*64 + row)*D_ + kh*32);
        #pragma unroll
        for (int g = 0; g < 4; g++) {
            uint4 h, l;
            pack8(src[2*g], src[2*g+1], h, l);
            const size_t o = ((size_t)(pt*16 + kh*4 + g)*64 + row)*8;
            *(uint4*)(khi + o) = h;
            *(uint4*)(klo + o) = l;
        }
    } else {
        const int t = (blockIdx.x - 1024) * 256 + threadIdx.x;  // 0..2047
        const int n = t >> 2, kst = t & 3;
        const float4* src = (const float4*)(emb + (size_t)n * D_ + kst * 32);
        float ss = 0.f;
        #pragma unroll
        for (int g = 0; g < 4; g++) {
            const float4 a = src[2*g], b = src[2*g+1];
            ss += a.x*a.x + a.y*a.y + a.z*a.z + a.w*a.w
                + b.x*b.x + b.y*b.y + b.z*b.z + b.w*b.w;
            uint4 h, l;
            pack8(a, b, h, l);
            const int f = ((n >> 4) * 4 + kst) * 4 + g;
            *(uint4*)(ehi + (size_t)f*128 + (size_t)(n & 15)*8) = h;
            *(uint4*)(elo + (size_t)f*128 + (size_t)(n & 15)*8) = l;
        }
        ss += __shfl_xor(ss, 1);
        ss += __shfl_xor(ss, 2);
        if (kst == 0) sq[n] = ss;
    }
}

// ---------------------------------------------------------------------------
// kA: barrier-free transposed MFMA GEMM (M = n, N = p), ONE chunk per wave.
// Grid 2048: pt = b & 1023, chunk-half = b >> 10 — tile-sharing block pairs
// are 1024 apart (== 0 mod 8) -> same XCD under round-robin -> L2 sharing.
// Straight-line software pipeline: B-frags (HBM-streamed) double-buffered,
// loadB(k+1) issues before the MFMAs of kstep k. hi/lo 3-pass MFMA.
// ---------------------------------------------------------------------------
__global__ __launch_bounds__(256) void kA(const float* __restrict__ sq,
                                          const unsigned short* __restrict__ ehi,
                                          const unsigned short* __restrict__ elo,
                                          const unsigned short* __restrict__ khi,
                                          const unsigned short* __restrict__ klo,
                                          u64* __restrict__ bits,
                                          float* __restrict__ sfirst,
                                          float* __restrict__ slast,
                                          unsigned* __restrict__ mins,
                                          unsigned short* __restrict__ mini16)
{
    const int tid  = threadIdx.x;
    const int lane = tid & 63;
    const int wv   = tid >> 6;
    const int m    = lane & 15;               // p within 16-tile
    const int q    = lane >> 4;               // quad
    const int pt   = blockIdx.x & 1023;
    const int p0   = pt * 64;
    const int ch   = (blockIdx.x >> 10) * 4 + wv;   // chunk 0..7
    const int nb   = ch * 64;

    floatx4 acc[4][4];
    #pragma unroll
    for (int i = 0; i < 4; i++)
        #pragma unroll
        for (int j = 0; j < 4; j++)
            #pragma unroll
            for (int r = 0; r < 4; r++) acc[i][j][r] = 0.f;

    bf16x8 ah[4], al[4], bh0[4], bl0[4], bh1[4], bl1[4];

    auto loadA = [&](int kst) {
        #pragma unroll
        for (int i = 0; i < 4; i++) {
            const int off = (((ch*4 + i) * 4 + kst) * 4 + q) * 128 + m*8;
            ah[i] = *(const bf16x8*)(ehi + off);
            al[i] = *(const bf16x8*)(elo + off);
        }
    };
    auto loadB = [&](int kst, bf16x8* BH, bf16x8* BL) {
        #pragma unroll
        for (int j = 0; j < 4; j++) {
            const int off = ((pt*16 + kst*4 + q) * 64 + j*16 + m) * 8;
            BH[j] = *(const bf16x8*)(khi + off);
            BL[j] = *(const bf16x8*)(klo + off);
        }
    };
    auto mfma3 = [&](const bf16x8* BH, const bf16x8* BL) {
        #pragma unroll
        for (int i = 0; i < 4; i++)
            #pragma unroll
            for (int j = 0; j < 4; j++)
                acc[i][j] = __builtin_amdgcn_mfma_f32_16x16x32_bf16(ah[i], BH[j], acc[i][j], 0, 0, 0);
        #pragma unroll
        for (int i = 0; i < 4; i++)
            #pragma unroll
            for (int j = 0; j < 4; j++)
                acc[i][j] = __builtin_amdgcn_mfma_f32_16x16x32_bf16(ah[i], BL[j], acc[i][j], 0, 0, 0);
        #pragma unroll
        for (int i = 0; i < 4; i++)
            #pragma unroll
            for (int j = 0; j < 4; j++)
                acc[i][j] = __builtin_amdgcn_mfma_f32_16x16x32_bf16(al[i], BH[j], acc[i][j], 0, 0, 0);
    };

    loadB(0, bh0, bl0);
    loadA(0);
    loadB(1, bh1, bl1);      // prefetch kst1 B under kst0 MFMAs
    mfma3(bh0, bl0);
    loadA(1);
    loadB(2, bh0, bl0);      // prefetch kst2 B under kst1 MFMAs
    mfma3(bh1, bl1);
    loadA(2);
    loadB(3, bh1, bl1);      // prefetch kst3 B under kst2 MFMAs
    mfma3(bh0, bl0);
    loadA(3);
    mfma3(bh1, bl1);

    // ---- epilogue (register-local; non-terminal bit63 patched in kB) ----
    float sa[4][4];
    #pragma unroll
    for (int i = 0; i < 4; i++) {
        const float4 s4 = *(const float4*)(sq + nb + i*16 + q*4);
        sa[i][0]=s4.x; sa[i][1]=s4.y; sa[i][2]=s4.z; sa[i][3]=s4.w;
    }
    #pragma unroll
    for (int j = 0; j < 4; j++) {
        float S[4][4];
        #pragma unroll
        for (int i = 0; i < 4; i++)
            #pragma unroll
            for (int r = 0; r < 4; r++)
                S[i][r] = fmaf(-2.f, acc[i][j][r], sa[i][r]);

        // neighbor S at quad/tile boundaries
        float nq[4], ni[4];
        #pragma unroll
        for (int i = 0; i < 4; i++) nq[i] = __shfl_down(S[i][0], 16);
        #pragma unroll
        for (int i = 0; i < 3; i++) ni[i] = __shfl(S[i+1][0], m);
        ni[3] = 0.f;

        u64 w = 0;
        #pragma unroll
        for (int i = 0; i < 4; i++) {
            #pragma unroll
            for (int r = 0; r < 3; r++)
                w |= (u64)(S[i][r] <= S[i][r+1]) << (16*i + 4*q + r);
            if (!(i == 3 && q == 3)) {
                const float nxt = (q < 3) ? nq[i] : ni[i];
                w |= (u64)(S[i][3] <= nxt) << (16*i + 4*q + 3);
            }
        }
        if (ch == 7 && q == 3) w |= 1ULL << 63;   // n=511 clip -> stay
        w |= shflx64(w, 16);
        w |= shflx64(w, 32);

        // chunk argmin, EXACT (first-index tie-break)
        float mv = S[0][0]; int mi_ = nb + q*4;
        #pragma unroll
        for (int i = 0; i < 4; i++)
            #pragma unroll
            for (int r = 0; r < 4; r++) {
                if (i == 0 && r == 0) continue;
                const int nid = nb + 16*i + 4*q + r;
                if (S[i][r] < mv) { mv = S[i][r]; mi_ = nid; }
            }
        #pragma unroll
        for (int d = 16; d <= 32; d <<= 1) {
            const float v2 = __shfl_xor(mv, d);
            const int   i2 = __shfl_xor(mi_, d);
            if (v2 < mv || (v2 == mv && i2 < mi_)) { mv = v2; mi_ = i2; }
        }

        const size_t pg = (size_t)(p0 + j*16 + m);
        if (q == 0) {
            bits  [pg*8 + ch] = w;
            sfirst[pg*8 + ch] = S[0][0];
            mins  [pg*8 + ch] = sortkey(mv);
            mini16[pg*8 + ch] = (unsigned short)mi_;
        }
        if (q == 3) slast[pg*8 + ch] = S[3][3];
    }
}

// ---------------------------------------------------------------------------
// kB: one wave per b. ind0 from EXACT u64-key argmin at t=0, then 16 windows
// of 64 scan steps; double-buffered window prefetch + 7-boundary bit63 patch
// in registers + 64 unrolled readlane scan steps (scalar pipe).
// ---------------------------------------------------------------------------
struct KBwin { u64 W[8]; float F[8]; float L[8]; };

__global__ __launch_bounds__(64) void kB(const float* __restrict__ ks,
                                         const float* __restrict__ emb,
                                         const unsigned char* __restrict__ mask,
                                         const u64* __restrict__ bits,
                                         const float* __restrict__ sfirst,
                                         const float* __restrict__ slast,
                                         const unsigned* __restrict__ mins,
                                         const unsigned short* __restrict__ mini16,
                                         int* __restrict__ enci,
                                         float* __restrict__ out)
{
    const int b    = blockIdx.x;
    const int lane = threadIdx.x;
    const size_t p0 = (size_t)b * T_;

    // ind0: S[512] exact + 8 exact chunk keys
    const float2 e = ((const float2*)(emb + (size_t)512*D_))[lane];
    const float2 k = ((const float2*)(ks  + p0*D_))[lane];
    float s5 = e.x*(e.x - 2.f*k.x) + e.y*(e.y - 2.f*k.y);
    #pragma unroll
    for (int m = 32; m >= 1; m >>= 1) s5 += __shfl_xor(s5, m);

    u64 kk = ~0ULL;
    if (lane < 8)       kk = ((u64)mins[p0*8 + lane] << 32) | (u64)mini16[p0*8 + lane];
    else if (lane == 8) kk = ((u64)sortkey(s5) << 32) | 512ULL;
    #pragma unroll
    for (int d = 1; d <= 8; d <<= 1) {
        const u64 o = shflx64(kk, d);
        kk = (o < kk) ? o : kk;
    }
    const int mi = __shfl((int)(unsigned)(kk & 0xffffffffULL), 0);
    int cur = (mi < NE) ? mi : NE - 1;
    if (mask[b]) cur = 0;
    if (lane == 0) { enci[p0] = cur; out[O_ENC + p0] = (float)cur; }

    KBwin wa, wb;

    auto loadwin = [&](KBwin& d, int t0) {
        const int t = t0 + lane;
        if (t < T_) {
            const ulonglong2* bp = (const ulonglong2*)(bits + (p0 + t)*8);
            const ulonglong2 w01 = bp[0], w23 = bp[1], w45 = bp[2], w67 = bp[3];
            d.W[0]=w01.x; d.W[1]=w01.y; d.W[2]=w23.x; d.W[3]=w23.y;
            d.W[4]=w45.x; d.W[5]=w45.y; d.W[6]=w67.x; d.W[7]=w67.y;
            const float4* fp = (const float4*)(sfirst + (p0 + t)*8);
            const float4 f0 = fp[0], f1 = fp[1];
            d.F[0]=f0.x; d.F[1]=f0.y; d.F[2]=f0.z; d.F[3]=f0.w;
            d.F[4]=f1.x; d.F[5]=f1.y; d.F[6]=f1.z; d.F[7]=f1.w;
            const float4* lp = (const float4*)(slast + (p0 + t)*8);
            const float4 l0 = lp[0], l1 = lp[1];
            d.L[0]=l0.x; d.L[1]=l0.y; d.L[2]=l0.z; d.L[3]=l0.w;
            d.L[4]=l1.x; d.L[5]=l1.y; d.L[6]=l1.z; d.L[7]=l1.w;
        } else {
            #pragma unroll
            for (int c = 0; c < 8; c++) { d.W[c] = ~0ULL; d.F[c] = 1.f; d.L[c] = 0.f; }
        }
    };

    auto scanwin = [&](KBwin& d, int t0) {
        #pragma unroll
        for (int c = 0; c < 7; c++)
            d.W[c] |= (u64)(d.L[c] <= d.F[c+1]) << 63;

        const int w0   = cur >> 6;
        const int off0 = cur & 63;
        u64 a = d.W[0];
        #pragma unroll
        for (int c = 1; c < 8; c++) a = (w0 == c) ? d.W[c] : a;
        u64 bn = ~0ULL;
        #pragma unroll
        for (int c = 1; c < 8; c++) bn = (w0 == c-1) ? d.W[c] : bn;
        const u64 u = (off0 == 0) ? a : ((a >> off0) | (bn << (64 - off0)));

        const unsigned ulo = (unsigned)u;
        const unsigned uhi = (unsigned)(u >> 32);
        int doff = 0;
        int myenc = cur;
        #pragma unroll
        for (int j = 0; j < 64; j++) {
            const unsigned slo = (unsigned)__builtin_amdgcn_readlane((int)ulo, j);
            const unsigned shi = (unsigned)__builtin_amdgcn_readlane((int)uhi, j);
            const u64 word = ((u64)shi << 32) | slo;
            const int bit = (int)((word >> doff) & 1ULL);
            doff += 1 - bit;
            if (lane == j) myenc = cur + doff;
        }
        cur += doff;
        const int t = t0 + lane;
        if (t < T_) {
            enci[p0 + t] = myenc;
            out[O_ENC + p0 + t] = (float)myenc;
        }
    };

    loadwin(wa, 1);
    #pragma unroll 1
    for (int wp = 0; wp < 8; wp++) {
        const int t0a = 1 + wp*128;
        loadwin(wb, t0a + 64);
        scanwin(wa, t0a);
        if (wp < 7) loadwin(wa, t0a + 128);
        scanwin(wb, t0a + 64);
    }
}

// ---------------------------------------------------------------------------
// kC: one wave per position, quad-split. Quad q computes one dot:
// q0: S[eh], q1: S[en], q2: S[512], q3: ||ks||^2. Global argmin via EXACT
// u64 keys. pm is SELECTED (pm=ph / pn / p5) when mi hits a special case —
// bitwise-guaranteed equality regardless of codegen/contraction. Recompute
// only for genuinely distinct mi (real gap -> rounding-safe).
// ---------------------------------------------------------------------------
__global__ __launch_bounds__(256) void kC(const float* __restrict__ ks,
                                          const float* __restrict__ emb,
                                          const int* __restrict__ enci,
                                          const unsigned* __restrict__ mins,
                                          const unsigned short* __restrict__ mini16,
                                          float* __restrict__ out,
                                          float* __restrict__ energy)
{
    const int lane = threadIdx.x & 63;
    const size_t p = (size_t)blockIdx.x * 4 + (threadIdx.x >> 6);
    const int q  = lane >> 4;
    const int qm = lane & 15;

    const int eh = enci[p];
    const int en = (eh + 1 < NE) ? eh + 1 : NE - 1;
    const int row = (q == 0) ? eh : ((q == 1) ? en : 512);

    const float4* ksp = (const float4*)(ks + p*D_);
    const float4 k1 = ksp[qm*2], k2 = ksp[qm*2 + 1];
    const float4* ep = (const float4*)(emb + (size_t)row*D_);
    const float4 e1 = ep[qm*2], e2 = ep[qm*2 + 1];

    float d;
    if (q == 3) {
        d = k1.x*k1.x + k1.y*k1.y + k1.z*k1.z + k1.w*k1.w
          + k2.x*k2.x + k2.y*k2.y + k2.z*k2.z + k2.w*k2.w;
    } else {
        d = e1.x*(e1.x - 2.f*k1.x) + e1.y*(e1.y - 2.f*k1.y)
          + e1.z*(e1.z - 2.f*k1.z) + e1.w*(e1.w - 2.f*k1.w)
          + e2.x*(e2.x - 2.f*k2.x) + e2.y*(e2.y - 2.f*k2.y)
          + e2.z*(e2.z - 2.f*k2.z) + e2.w*(e2.w - 2.f*k2.w);
    }
    #pragma unroll
    for (int s = 1; s <= 8; s <<= 1) d += __shfl_xor(d, s);

    const float ph  = __shfl(d, 0);
    const float pn  = __shfl(d, 16);
    const float p5  = __shfl(d, 32);
    const float sqk = __shfl(d, 48);

    // global argmin via EXACT u64 keys (8 chunk keys + S[512] key)
    u64 kk = ~0ULL;
    if (lane < 8)       kk = ((u64)mins[p*8 + lane] << 32) | (u64)mini16[p*8 + lane];
    else if (lane == 8) kk = ((u64)sortkey(p5) << 32) | 512ULL;
    #pragma unroll
    for (int s = 1; s <= 8; s <<= 1) {
        const u64 o = shflx64(kk, s);
        kk = (o < kk) ? o : kk;
    }
    const int mi = __shfl((int)(unsigned)(kk & 0xffffffffULL), 0);

    // pm: SELECT for special cases (bitwise equality), recompute otherwise
    float pm;
    if (mi == eh)      pm = ph;
    else if (mi == en) pm = pn;
    else if (mi == 512) pm = p5;
    else {
        const float4* mp = (const float4*)(emb + (size_t)mi*D_);
        const float4 m1 = mp[qm*2], m2 = mp[qm*2 + 1];
        float dm = m1.x*(m1.x - 2.f*k1.x) + m1.y*(m1.y - 2.f*k1.y)
                 + m1.z*(m1.z - 2.f*k1.z) + m1.w*(m1.w - 2.f*k1.w)
                 + m2.x*(m2.x - 2.f*k2.x) + m2.y*(m2.y - 2.f*k2.y)
                 + m2.z*(m2.z - 2.f*k2.z) + m2.w*(m2.w - 2.f*k2.w);
        #pragma unroll
        for (int s = 1; s <= 8; s <<= 1) dm += __shfl_xor(dm, s);
        pm = __shfl(dm, 0);
    }

    // key_hard: quad0 holds emb[eh] slices; kh = ks + (emb - ks) in fp32
    if (q == 0) {
        float4 o1, o2;
        o1.x = k1.x + (e1.x - k1.x); o1.y = k1.y + (e1.y - k1.y);
        o1.z = k1.z + (e1.z - k1.z); o1.w = k1.w + (e1.w - k1.w);
        o2.x = k2.x + (e2.x - k2.x); o2.y = k2.y + (e2.y - k2.y);
        o2.z = k2.z + (e2.z - k2.z); o2.w = k2.w + (e2.w - k2.w);
        ((float4*)(out + p*D_))[qm*2]     = o1;
        ((float4*)(out + p*D_))[qm*2 + 1] = o2;
    }

    if (lane == 0) {
        const float lh = 1.2f * (sqk + ph);
        const float ln = 1.2f * (sqk + pn);
        const float lm = 1.2f * (sqk + pm);
        out[O_LH + p] = lh - ln - ((pm < ph) ? lm : 0.f);
        out[O_LN + p] = ln - lh - ((pm < pn) ? lm : 0.f);
        energy[p] = 1.2f * (pn - ph);
    }
}

// ---------------------------------------------------------------------------
// kD1: per-256-position partial sums (energy, energy-descent terms)
// ---------------------------------------------------------------------------
__global__ __launch_bounds__(256) void kD1(const float* __restrict__ energy,
                                           const int* __restrict__ enci,
                                           double2* __restrict__ part)
{
    __shared__ double sA[256], sB[256];
    const int p = blockIdx.x * 256 + threadIdx.x;
    const float e = energy[p];
    double se = (double)e;
    double sl = 0.0;
    if ((p & (T_-1)) < T_-1) {
        const float ec = (enci[p+1] == enci[p]) ? (energy[p+1] - e) : 0.f;
        sl = (double)fmaxf(ec + (float)(1e-6/512.0), 0.f);
    }
    sA[threadIdx.x] = se; sB[threadIdx.x] = sl;
    __syncthreads();
    for (int s = 128; s >= 1; s >>= 1) {
        if (threadIdx.x < (unsigned)s) {
            sA[threadIdx.x] += sA[threadIdx.x+s];
            sB[threadIdx.x] += sB[threadIdx.x+s];
        }
        __syncthreads();
    }
    if (threadIdx.x == 0) { part[blockIdx.x] = make_double2(sA[0], sB[0]); }
}

// ---------------------------------------------------------------------------
// kD2: final reduce of 256 partials + v = max over b of (enc_last - enc_first)
// ---------------------------------------------------------------------------
__global__ __launch_bounds__(256) void kD2(const double2* __restrict__ part,
                                           const int* __restrict__ enci,
                                           float* __restrict__ out)
{
    __shared__ double sA[256], sB[256];
    const double2 pv = part[threadIdx.x];
    sA[threadIdx.x] = pv.x; sB[threadIdx.x] = pv.y;
    __syncthreads();
    for (int s = 128; s >= 1; s >>= 1) {
        if (threadIdx.x < (unsigned)s) {
            sA[threadIdx.x] += sA[threadIdx.x+s];
            sB[threadIdx.x] += sB[threadIdx.x+s];
        }
        __syncthreads();
    }
    if (threadIdx.x < 64) {
        int v = enci[(size_t)threadIdx.x*T_ + T_-1] - enci[(size_t)threadIdx.x*T_];
        #pragma unroll
        for (int m = 32; m >= 1; m >>= 1) {
            const int v2 = __shfl_xor(v, m);
            v = (v2 > v) ? v2 : v;
        }
        if (threadIdx.x == 0) {
            out[O_V]   = (float)v;
            out[O_EM]  = (float)(sA[0] / (double)P_);
            out[O_LED] = (float)(sB[0] / (double)(B_*(T_-1)));
        }
    }
}

// ---------------------------------------------------------------------------
extern "C" void kernel_launch(void* const* d_in, const int* in_sizes, int n_in,
                              void* d_out, int out_size, void* d_ws, size_t ws_size,
                              hipStream_t stream)
{
    const float* ks  = (const float*)d_in[0];
    const float* emb = (const float*)d_in[1];
    const unsigned char* mask = (const unsigned char*)d_in[2];

    float* out = (float*)d_out;
    char* w = (char*)d_ws;
    u64*      bits   = (u64*)     (w);                                    // 4 MB
    float*    sfirst = (float*)   (w + (size_t) 4*1024*1024);             // 2 MB
    float*    slast  = (float*)   (w + (size_t) 6*1024*1024);             // 2 MB
    unsigned* mins   = (unsigned*)(w + (size_t) 8*1024*1024);             // 2 MB
    unsigned short* mini16 = (unsigned short*)(w + (size_t)10*1024*1024); // 1 MB
    int*      enci   = (int*)     (w + (size_t)11*1024*1024);             // 256 KB
    float*    energy = (float*)   (w + (size_t)11*1024*1024 + 256*1024);  // 256 KB
    float*    sq     = (float*)   (w + (size_t)11*1024*1024 + 512*1024);  // 4 KB
    double2*  part   = (double2*) (w + (size_t)11*1024*1024 + 516*1024);  // 4 KB
    unsigned short* ehi = (unsigned short*)(w + (size_t)11*1024*1024 + 640*1024); // 128 KB
    unsigned short* elo = (unsigned short*)(w + (size_t)11*1024*1024 + 768*1024); // 128 KB
    // ks bf16 frags live in d_out's key_hard region (32 MiB) as scratch:
    // written by kFG, read by kA, overwritten by kC. Stream-ordered, no hazard.
    unsigned short* khi = (unsigned short*)d_out;                          // 16 MiB
    unsigned short* klo = (unsigned short*)((char*)d_out + (size_t)16*1024*1024); // 16 MiB

    kFG<<<1032, 256, 0, stream>>>(ks, emb, ehi, elo, sq, khi, klo);
    kA <<<2048, 256, 0, stream>>>(sq, ehi, elo, khi, klo, bits, sfirst, slast, mins, mini16);
    kB <<<B_,   64,  0, stream>>>(ks, emb, mask, bits, sfirst, slast, mins, mini16, enci, out);
    kC <<<P_/4, 256, 0, stream>>>(ks, emb, enci, mins, mini16, out, energy);
    kD1<<<256,  256, 0, stream>>>(energy, enci, part);
    kD2<<<1,    256, 0, stream>>>(part, enci, out);
}